// Round 3
// baseline (286.501 us; speedup 1.0000x reference)
//
#include <hip/hip_runtime.h>
#include <hip/hip_bf16.h>
#include <stdint.h>

#define L1DIM 1536
#define NOUT  144           // 128 (W1) + 16 (Wf) layer-1 outputs
#define MTILE 16            // rows per block (single bucket per block after sort)
#define NITER 12            // k-steps of 32 per wave (wave owns k-quarter = 384)
#define PERMN 16512         // 1032 * 16 worst-case padded rows
#define GMAIN 1032

typedef __bf16 bf16;
typedef __bf16 bf16x8 __attribute__((ext_vector_type(8)));
typedef float  floatx4 __attribute__((ext_vector_type(4)));

// ---------------------------------------------------------------------------
// K1 (single prepass launch, 109 blocks):
//   blocks 0..107 : pack [W1;Wf] -> pw in MFMA B-fragment order
//                   pw[(o*144+n)*8 + j] = W[n][o*8+j]
//   block 108     : bucket sort of all 16384 rows in ONE block:
//                   histogram -> padded prefix (x16) -> ballot-aggregated
//                   scatter into perm; meta[0] = padded_total; pads = -1.
// ---------------------------------------------------------------------------
__global__ __launch_bounds__(256) void k_prep(
    const float* __restrict__ W1, const float* __restrict__ Wf,
    bf16* __restrict__ pw, const int* __restrict__ lsidx,
    int* __restrict__ perm, int* __restrict__ meta)
{
    const int gb  = blockIdx.x;
    const int tid = threadIdx.x;

    if (gb < 108) {
        int t = gb * 256 + tid;              // 0 .. 27647
        int n = t / 192;                     // output feature 0..143
        int o = t % 192;                     // k-octet 0..191
        const float* src = (n < 128) ? (W1 + (size_t)n * L1DIM + o * 8)
                                     : (Wf + (size_t)(n - 128) * L1DIM + o * 8);
        float4 s0 = ((const float4*)src)[0];
        float4 s1 = ((const float4*)src)[1];
        bf16x8 v;
        v[0] = (bf16)s0.x; v[1] = (bf16)s0.y; v[2] = (bf16)s0.z; v[3] = (bf16)s0.w;
        v[4] = (bf16)s1.x; v[5] = (bf16)s1.y; v[6] = (bf16)s1.z; v[7] = (bf16)s1.w;
        *(bf16x8*)(pw + ((size_t)o * NOUT + n) * 8) = v;
        return;
    }

    // ---------------- sorter block ----------------
    __shared__ int cnt[8];
    __shared__ int cur[8];
    const int ln = tid & 63;

    if (tid < 8) cnt[tid] = 0;
    for (int i = tid; i < PERMN; i += 256) perm[i] = -1;
    __syncthreads();

    // histogram: per-thread static-index counters, wave shfl-reduce, 8 atomics/wave
    int c0=0,c1=0,c2=0,c3=0,c4=0,c5=0,c6=0,c7=0;
    for (int s = 0; s < 64; s++) {
        const int b = lsidx[s * 256 + tid];
        c0 += (b == 0); c1 += (b == 1); c2 += (b == 2); c3 += (b == 3);
        c4 += (b == 4); c5 += (b == 5); c6 += (b == 6); c7 += (b == 7);
    }
#define WRED(c_, b_)                                                       \
    { int v = c_;                                                          \
      v += __shfl_xor(v, 1);  v += __shfl_xor(v, 2);  v += __shfl_xor(v, 4);\
      v += __shfl_xor(v, 8);  v += __shfl_xor(v, 16); v += __shfl_xor(v, 32);\
      if (ln == 0) atomicAdd(&cnt[b_], v); }
    WRED(c0,0) WRED(c1,1) WRED(c2,2) WRED(c3,3)
    WRED(c4,4) WRED(c5,5) WRED(c6,6) WRED(c7,7)
#undef WRED
    __syncthreads();

    if (tid == 0) {
        int o = 0;
#pragma unroll
        for (int b = 0; b < 8; b++) { cur[b] = o; o += (cnt[b] + 15) & ~15; }
        meta[0] = o;
    }
    __syncthreads();

    // scatter: ballot-aggregated LDS cursor atomics
    for (int s = 0; s < 64; s++) {
        const int i = s * 256 + tid;
        const int b = lsidx[i];
#pragma unroll
        for (int bb = 0; bb < 8; bb++) {
            unsigned long long m = __ballot(b == bb);
            if (b == bb) {
                int leader = __ffsll(m) - 1;
                int base = 0;
                if (ln == leader) base = atomicAdd(&cur[bb], (int)__popcll(m));
                base = __shfl(base, leader);
                perm[base + (int)__popcll(m & ((1ull << ln) - 1))] = i;
            }
        }
    }
}

__device__ __forceinline__ bf16x8 cvt8(float4 a, float4 b) {
    bf16x8 r;
    r[0] = (bf16)a.x; r[1] = (bf16)a.y; r[2] = (bf16)a.z; r[3] = (bf16)a.w;
    r[4] = (bf16)b.x; r[5] = (bf16)b.y; r[6] = (bf16)b.z; r[7] = (bf16)b.w;
    return r;
}

// ---------------------------------------------------------------------------
// Main kernel: barrier-free streaming k-loop.
//  - Block = 16 bucket-sorted rows, 4 waves = 4-way k-split (wave wv owns
//    k in [wv*384, wv*384+384), 12 steps of 32).
//  - A loaded DIRECTLY global->VGPR in MFMA fragment layout: lane (q,lm)
//    reads 32 B contiguous of row perm[R0+lm]; per instr-pair the wave covers
//    16 rows x 128 B contiguous. x read exactly once, no LDS, no barriers.
//  - B: 2 fragments/iter (bucket tile + Wf tile) from L2-resident pw.
//  - Single __syncthreads pair at the end for k-quarter reduce + epilogue.
// ---------------------------------------------------------------------------
__global__ __launch_bounds__(256, 4) void layerstacks_main(
    const float* __restrict__ x, const int* __restrict__ lsidx,
    const bf16* __restrict__ pw, const int* __restrict__ perm,
    const int* __restrict__ meta,
    const float* __restrict__ b1, const float* __restrict__ bf_,
    const float* __restrict__ W2, const float* __restrict__ b2,
    const float* __restrict__ Wo, const float* __restrict__ bo,
    float* __restrict__ out)
{
    // floats: [0..2111] ep4[4][16][33] | [2112..4031] W2 slice | [4032..4095] Wo
    //         [4096..4159] b2
    __shared__ float sm[4160];

    const int tid  = threadIdx.x;
    const int wv   = tid >> 6;
    const int ln   = tid & 63;
    const int quad = ln >> 4;
    const int lm   = ln & 15;

    const int R0 = blockIdx.x * MTILE;
    if (R0 >= meta[0]) return;

    const int bkt = lsidx[perm[R0]];          // block-uniform (row 0 is real)

    int pr = perm[R0 + lm];                   // this lane's source row
    if (pr < 0) pr = 0;                       // pad rows read row 0 (discarded)

    const float* ax  = x + (size_t)pr * L1DIM + wv * 384 + quad * 8;
    const bf16*  bw  = pw + (size_t)(wv * 48 + quad) * (NOUT * 8);
    const bf16*  bbS = bw + (size_t)(bkt * 16 + lm) * 8;   // bucket tile
    const bf16*  bbF = bw + (size_t)(128 + lm) * 8;        // Wf tile

    floatx4 acc0 = (floatx4){0.f, 0.f, 0.f, 0.f};
    floatx4 acc1 = (floatx4){0.f, 0.f, 0.f, 0.f};

#pragma unroll
    for (int ki = 0; ki < NITER; ki++) {
        float4 a0 = *(const float4*)(ax + ki * 32);
        float4 a1 = *(const float4*)(ax + ki * 32 + 4);
        bf16x8 bf0 = *(const bf16x8*)(bbS + (size_t)ki * 4 * NOUT * 8);
        bf16x8 bf1 = *(const bf16x8*)(bbF + (size_t)ki * 4 * NOUT * 8);
        bf16x8 af = cvt8(a0, a1);
        acc0 = __builtin_amdgcn_mfma_f32_16x16x32_bf16(af, bf0, acc0, 0, 0, 0);
        acc1 = __builtin_amdgcn_mfma_f32_16x16x32_bf16(af, bf1, acc1, 0, 0, 0);
    }

    // ---- per-wave partials (C layout: row=quad*4+r, col=lm) ----
#pragma unroll
    for (int r = 0; r < 4; r++) {
        const int row = quad * 4 + r;
        sm[(wv * 16 + row) * 33 + lm]      = acc0[r];
        sm[(wv * 16 + row) * 33 + 16 + lm] = acc1[r];
    }
    // stage block-uniform W2/Wo/b2 slices
    {
        const float* w2src = W2 + (size_t)bkt * 64 * 30;
        for (int i = tid; i < 1920; i += 256) sm[2112 + i] = w2src[i];
        if (tid < 64) {
            sm[4032 + tid] = Wo[bkt * 64 + tid];
            sm[4096 + tid] = b2[bkt * 64 + tid];
        }
    }
    __syncthreads();

    // ---- reduce 4 k-quarter partials ----
    {
        const int col = tid & 31;
        const int rr  = tid >> 5;            // 0..7
#pragma unroll
        for (int p = 0; p < 2; p++) {
            const int row = rr + p * 8;
            sm[row * 33 + col] = sm[row * 33 + col] + sm[528 + row * 33 + col]
                               + sm[1056 + row * 33 + col] + sm[1584 + row * 33 + col];
        }
    }
    __syncthreads();

    // ---- epilogue: 8 threads per row, 16 rows ----
    if (tid < 128) {
        const int er  = tid >> 3;
        const int sub = tid & 7;
        const int pr2 = perm[R0 + er];
        if (pr2 >= 0) {
            const float l1c15 = sm[er * 33 + 15] + b1[bkt * 16 + 15];
            const float l1f15 = sm[er * 33 + 31] + bf_[15];

            float l1x[30];
#pragma unroll
            for (int j = 0; j < 15; j++) {
                float tj = (sm[er * 33 + j] + b1[bkt * 16 + j])
                         + (sm[er * 33 + 16 + j] + bf_[j]);
                float sq = tj * tj * (127.0f / 128.0f);
                l1x[j]      = fminf(fmaxf(sq, 0.f), 1.f);
                l1x[15 + j] = fminf(fmaxf(tj, 0.f), 1.f);
            }

            float part = 0.f;
#pragma unroll
            for (int o = 0; o < 8; o++) {
                const int ol = sub * 8 + o;
                const float* wrow = &sm[2112 + ol * 30];
                float a = sm[4096 + ol];
#pragma unroll
                for (int j2 = 0; j2 < 15; j2++) {
                    float2 w = *(const float2*)&wrow[2 * j2];
                    a += l1x[2 * j2] * w.x + l1x[2 * j2 + 1] * w.y;
                }
                a = fminf(fmaxf(a, 0.f), 1.f);
                part += a * sm[4032 + ol];
            }
            part += __shfl_xor(part, 1);
            part += __shfl_xor(part, 2);
            part += __shfl_xor(part, 4);
            if (sub == 0) out[pr2] = part + bo[bkt] + l1c15 + l1f15;
        }
    }
}

extern "C" void kernel_launch(void* const* d_in, const int* in_sizes, int n_in,
                              void* d_out, int out_size, void* d_ws, size_t ws_size,
                              hipStream_t stream) {
    const float* x   = (const float*)d_in[0];
    const int*   idx = (const int*)  d_in[1];
    const float* W1  = (const float*)d_in[2];
    const float* b1  = (const float*)d_in[3];
    const float* Wf  = (const float*)d_in[4];
    const float* bf  = (const float*)d_in[5];
    const float* W2  = (const float*)d_in[6];
    const float* b2  = (const float*)d_in[7];
    const float* Wo  = (const float*)d_in[8];
    const float* bo  = (const float*)d_in[9];
    float* out = (float*)d_out;

    // workspace: pw (442368 B) | perm (16512 ints) | meta (1 int)
    bf16* pw   = (bf16*)d_ws;
    int*  perm = (int*)((char*)d_ws + 442368);
    int*  meta = perm + PERMN;

    k_prep<<<dim3(109), dim3(256), 0, stream>>>(W1, Wf, pw, idx, perm, meta);
    layerstacks_main<<<dim3(GMAIN), dim3(256), 0, stream>>>(
        x, idx, pw, perm, meta, b1, bf, W2, b2, Wo, bo, out);
}

// Round 4
// 187.998 us; speedup vs baseline: 1.5240x; 1.5240x over previous
//
#include <hip/hip_runtime.h>
#include <hip/hip_bf16.h>
#include <stdint.h>

#define L1DIM 1536
#define NOUT  144           // 128 (W1) + 16 (Wf) layer-1 outputs
#define MTILE 16            // rows per block
#define NITER 12            // k-steps of 32 per wave (wave owns k-quarter = 384)

typedef __bf16 bf16;
typedef __bf16 bf16x8 __attribute__((ext_vector_type(8)));
typedef float  floatx4 __attribute__((ext_vector_type(4)));

// ---------------------------------------------------------------------------
// Pack [W1;Wf] (144 x 1536 fp32) -> bf16 in MFMA B-fragment order:
//   pw[(o*144+n)*8 + j] = W[n][o*8+j]   (16 B per (k-octet o, feature n))
// ---------------------------------------------------------------------------
__global__ __launch_bounds__(256) void pack_weights(
    const float* __restrict__ W1, const float* __restrict__ Wf,
    bf16* __restrict__ pw)
{
    int t = blockIdx.x * 256 + threadIdx.x;  // 0 .. 27647
    int n = t / 192;                         // output feature 0..143
    int o = t % 192;                         // k-octet 0..191
    const float* src = (n < 128) ? (W1 + (size_t)n * L1DIM + o * 8)
                                 : (Wf + (size_t)(n - 128) * L1DIM + o * 8);
    float4 s0 = ((const float4*)src)[0];
    float4 s1 = ((const float4*)src)[1];
    bf16x8 v;
    v[0] = (bf16)s0.x; v[1] = (bf16)s0.y; v[2] = (bf16)s0.z; v[3] = (bf16)s0.w;
    v[4] = (bf16)s1.x; v[5] = (bf16)s1.y; v[6] = (bf16)s1.z; v[7] = (bf16)s1.w;
    *(bf16x8*)(pw + ((size_t)o * NOUT + n) * 8) = v;
}

__device__ __forceinline__ bf16x8 cvt8(float4 a, float4 b) {
    bf16x8 r;
    r[0] = (bf16)a.x; r[1] = (bf16)a.y; r[2] = (bf16)a.z; r[3] = (bf16)a.w;
    r[4] = (bf16)b.x; r[5] = (bf16)b.y; r[6] = (bf16)b.z; r[7] = (bf16)b.w;
    return r;
}

// ---------------------------------------------------------------------------
// Main kernel: barrier-free streaming k-loop, NO row sort (9 B-tiles/iter).
//  - Block = 16 contiguous rows, 4 waves = 4-way k-split (wave wv owns
//    k in [wv*384, wv*384+384), 12 steps of 32). Grid 1024 = 4 blocks/CU,
//    16 waves/CU: latency hidden by TLP, zero barriers in the k-loop.
//  - A loaded DIRECTLY global->VGPR in MFMA fragment layout: lane (q,lm)
//    reads 32 B contiguous of row R0+lm; per iter the wave covers 16 rows
//    x 128 B. x is read exactly once; no LDS staging, no waitcnt games.
//  - B: 9 fragments/iter (buckets 0..7 + Wf) from L2-resident packed pw.
//    ~432 KB/block of L2 traffic overlaps the HBM stream.
//  - Per-wave bucket-gather into ep4[wv], one __syncthreads, 4-way reduce,
//    then the proven Round-1 epilogue (W2/Wo/b2 straight from global/L2).
// ---------------------------------------------------------------------------
__global__ __launch_bounds__(256, 4) void layerstacks_main(
    const float* __restrict__ x, const int* __restrict__ lsidx,
    const bf16* __restrict__ pw,
    const float* __restrict__ b1, const float* __restrict__ bf_,
    const float* __restrict__ W2, const float* __restrict__ b2,
    const float* __restrict__ Wo, const float* __restrict__ bo,
    float* __restrict__ out)
{
    __shared__ float ep4[4][MTILE][33];      // 8448 B

    const int tid  = threadIdx.x;
    const int wv   = tid >> 6;               // wave id == k-quarter
    const int ln   = tid & 63;
    const int quad = ln >> 4;
    const int lm   = ln & 15;

    const int R0 = blockIdx.x * MTILE;

    // A: lane (quad,lm) holds A[row=lm][k = quad*8 .. +8) of each 32-k slice
    const float* ax = x + (size_t)(R0 + lm) * L1DIM + wv * 384 + quad * 8;

    floatx4 acc[9];
#pragma unroll
    for (int i = 0; i < 9; i++) acc[i] = (floatx4){0.f, 0.f, 0.f, 0.f};

#pragma unroll
    for (int ki = 0; ki < NITER; ki++) {
        float4 a0 = *(const float4*)(ax + ki * 32);
        float4 a1 = *(const float4*)(ax + ki * 32 + 4);
        const bf16* bsl = pw + (size_t)(wv * 48 + ki * 4 + quad) * (NOUT * 8);
        bf16x8 af = cvt8(a0, a1);
#pragma unroll
        for (int t = 0; t < 9; t++) {
            bf16x8 bfr = *(const bf16x8*)(bsl + (size_t)(t * 16 + lm) * 8);
            acc[t] = __builtin_amdgcn_mfma_f32_16x16x32_bf16(af, bfr, acc[t], 0, 0, 0);
        }
    }

    // ---- per-wave bucket-gather (C layout: row = quad*4+r, col = lm) ----
    // tiles 0..7 = buckets 0..7 (features bkt*16..+16), tile 8 = Wf.
#pragma unroll
    for (int r = 0; r < 4; r++) {
        const int row = quad * 4 + r;
        const int bkt = lsidx[R0 + row];
        float c = acc[0][r];
#pragma unroll
        for (int t = 1; t < 8; t++) c = (bkt == t) ? acc[t][r] : c;
        ep4[wv][row][lm]      = c;           // selected-bucket col
        ep4[wv][row][16 + lm] = acc[8][r];   // shared (Wf) col
    }
    __syncthreads();

    // ---- reduce the 4 k-quarter partials into ep4[0] ----
    {
        const int col = tid & 31;
        const int rr  = tid >> 5;            // 0..7
#pragma unroll
        for (int p = 0; p < 2; p++) {
            const int row = rr + p * 8;
            ep4[0][row][col] = ep4[0][row][col] + ep4[1][row][col]
                             + ep4[2][row][col] + ep4[3][row][col];
        }
    }
    __syncthreads();

    // ---- epilogue: 8 threads per row, 16 rows (threads 0..127) ----
    if (tid < 128) {
        const int er   = tid >> 3;           // row in tile, 0..15
        const int sub  = tid & 7;            // output-group, 0..7
        const int grow = R0 + er;
        const int bkt  = lsidx[grow];

        const float l1c15 = ep4[0][er][15] + b1[bkt * 16 + 15];
        const float l1f15 = ep4[0][er][31] + bf_[15];

        float l1x[30];
#pragma unroll
        for (int j = 0; j < 15; j++) {
            float tj = (ep4[0][er][j] + b1[bkt * 16 + j])
                     + (ep4[0][er][16 + j] + bf_[j]);
            float sq = tj * tj * (127.0f / 128.0f);
            l1x[j]      = fminf(fmaxf(sq, 0.f), 1.f);
            l1x[15 + j] = fminf(fmaxf(tj, 0.f), 1.f);
        }

        float part = 0.f;
#pragma unroll
        for (int o = 0; o < 8; o++) {
            const int oi = bkt * 64 + sub * 8 + o;
            const float2* wrow = (const float2*)(W2 + oi * 30);   // 8B-aligned
            float a = b2[oi];
#pragma unroll
            for (int j2 = 0; j2 < 15; j2++) {
                float2 w = wrow[j2];
                a += l1x[2 * j2] * w.x + l1x[2 * j2 + 1] * w.y;
            }
            a = fminf(fmaxf(a, 0.f), 1.f);
            part += a * Wo[oi];
        }
        part += __shfl_xor(part, 1);
        part += __shfl_xor(part, 2);
        part += __shfl_xor(part, 4);
        if (sub == 0) out[grow] = part + bo[bkt] + l1c15 + l1f15;
    }
}

extern "C" void kernel_launch(void* const* d_in, const int* in_sizes, int n_in,
                              void* d_out, int out_size, void* d_ws, size_t ws_size,
                              hipStream_t stream) {
    const float* x   = (const float*)d_in[0];
    const int*   idx = (const int*)  d_in[1];
    const float* W1  = (const float*)d_in[2];
    const float* b1  = (const float*)d_in[3];
    const float* Wf  = (const float*)d_in[4];
    const float* bf  = (const float*)d_in[5];
    const float* W2  = (const float*)d_in[6];
    const float* b2  = (const float*)d_in[7];
    const float* Wo  = (const float*)d_in[8];
    const float* bo  = (const float*)d_in[9];
    float* out = (float*)d_out;
    bf16*  pw  = (bf16*)d_ws;                 // 442368 B of workspace

    pack_weights<<<dim3(108), dim3(256), 0, stream>>>(W1, Wf, pw);
    layerstacks_main<<<dim3(16384 / MTILE), dim3(256), 0, stream>>>(
        x, idx, pw, b1, bf, W2, b2, Wo, bo, out);
}